// Round 7
// baseline (426.116 us; speedup 1.0000x reference)
//
#include <hip/hip_runtime.h>
#include <math.h>

#define EPSD 1e-8
#define EPSF 1e-8f
#define IMG_H 512
#define IMG_W 512
#define TEX_W 1024
#define TEX_H 1024
#define RCH 256   // triangles per compaction chunk (indices only in LDS)

// ---------------------------------------------------------------------------
// Kernel 1: project vertices in f64 -> vpixd (x_pix, y_pix, z_cam)
// Matches a float64 numpy evaluation of the reference projection.
// ---------------------------------------------------------------------------
__global__ __launch_bounds__(256) void k_project(
    const float* __restrict__ v,
    const float* __restrict__ campos,
    const float* __restrict__ camrot,
    const float* __restrict__ focal,
    const float* __restrict__ princpt,
    double* __restrict__ vpixd,
    int N, int V) {
#pragma clang fp contract(off)
  int i = blockIdx.x * blockDim.x + threadIdx.x;
  if (i >= N * V) return;
  int n = i / V;
  const float* vv = v + (size_t)i * 3;
  double ax = (double)vv[0] - (double)campos[n * 3 + 0];
  double ay = (double)vv[1] - (double)campos[n * 3 + 1];
  double az = (double)vv[2] - (double)campos[n * 3 + 2];
  const float* R = camrot + (size_t)n * 9;
  double cx = ((double)R[0] * ax + (double)R[1] * ay) + (double)R[2] * az;
  double cy = ((double)R[3] * ax + (double)R[4] * ay) + (double)R[5] * az;
  double cz = ((double)R[6] * ax + (double)R[7] * ay) + (double)R[8] * az;
  double zz = fmax(cz, EPSD);
  double xd = cx / zz;
  double yd = cy / zz;
  const float* Fc = focal + (size_t)n * 4;
  double px = ((double)Fc[0] * xd + (double)Fc[1] * yd) + (double)princpt[n * 2 + 0];
  double py = ((double)Fc[2] * xd + (double)Fc[3] * yd) + (double)princpt[n * 2 + 1];
  vpixd[(size_t)i * 3 + 0] = px;
  vpixd[(size_t)i * 3 + 1] = py;
  vpixd[(size_t)i * 3 + 2] = cz;
}

// ---------------------------------------------------------------------------
// Kernel 2: per-triangle coefficient setup (f64).
// For pixel p: W_k = w_k*area = px*EA_k + py*EBn_k + EC_k
//   inside  <=> W0>=0 & W1>=0 & W2>=0      (area sign folded into coeffs)
//   zi = W0*R0 + W1*R1 + W2*R2,  R_k = 1/(area^2 * max(z_k,EPS))
// Invalid triangles: EA=EBn=0, EC=-1 -> never inside.
// Flat layout per (n,f), 12 doubles:
//  [EA0,EBn0,EC0, EA1,EBn1,EC1, EA2,EBn2,EC2, R0,R1,R2]
// ---------------------------------------------------------------------------
__global__ __launch_bounds__(256) void k_setup(
    const double* __restrict__ vpixd,
    const int* __restrict__ vi,
    double* __restrict__ tri,
    float4* __restrict__ bbox,
    int N, int V, int F) {
#pragma clang fp contract(off)
  int i = blockIdx.x * blockDim.x + threadIdx.x;
  if (i >= N * F) return;
  int n = i / F;
  int f = i - n * F;
  int i0 = vi[f * 3 + 0], i1 = vi[f * 3 + 1], i2 = vi[f * 3 + 2];
  const double* p0 = vpixd + ((size_t)n * V + i0) * 3;
  const double* p1 = vpixd + ((size_t)n * V + i1) * 3;
  const double* p2 = vpixd + ((size_t)n * V + i2) * 3;
  double x0 = p0[0], y0 = p0[1], z0 = p0[2];
  double x1 = p1[0], y1 = p1[1], z1 = p1[2];
  double x2 = p2[0], y2 = p2[1], z2 = p2[2];
  double A0 = y2 - y1, B0 = x2 - x1;
  double A1 = y0 - y2, B1 = x0 - x2;
  double A2 = y1 - y0, B2 = x1 - x0;
  double area = (x2 - x0) * A2 - (y2 - y0) * B2;
  bool valid = (fabs(area) > EPSD) && (z0 > EPSD) && (z1 > EPSD) && (z2 > EPSD);
  double s = area;
  double EA0 = 0.0, EBn0 = 0.0, EC0 = -1.0;
  double EA1 = 0.0, EBn1 = 0.0, EC1 = -1.0;
  double EA2 = 0.0, EBn2 = 0.0, EC2 = -1.0;
  double R0 = 0.0, R1 = 0.0, R2 = 0.0;
  if (valid) {
    EA0 = A0 * s; EBn0 = -(B0 * s); EC0 = (y1 * B0 - x1 * A0) * s;
    EA1 = A1 * s; EBn1 = -(B1 * s); EC1 = (y2 * B1 - x2 * A1) * s;
    EA2 = A2 * s; EBn2 = -(B2 * s); EC2 = (y0 * B2 - x0 * A2) * s;
    double s2 = s * s;
    R0 = 1.0 / (s2 * fmax(z0, EPSD));
    R1 = 1.0 / (s2 * fmax(z1, EPSD));
    R2 = 1.0 / (s2 * fmax(z2, EPSD));
  }
  double2* T = (double2*)(tri + (size_t)i * 12);
  T[0] = make_double2(EA0, EBn0);
  T[1] = make_double2(EC0, EA1);
  T[2] = make_double2(EBn1, EC1);
  T[3] = make_double2(EA2, EBn2);
  T[4] = make_double2(EC2, R0);
  T[5] = make_double2(R1, R2);
  float mnx = (float)fmin(x0, fmin(x1, x2));
  float mny = (float)fmin(y0, fmin(y1, y2));
  float mxx = (float)fmax(x0, fmax(x1, x2));
  float mxy = (float)fmax(y0, fmax(y1, y2));
  bbox[i] = make_float4(mnx, mny, mxx, mxy);
}

// ---------------------------------------------------------------------------
// Kernel 3: tiled rasterizer. 256-thread block covers a 16x32-pixel tile
// (2 px/thread, rows y and y+16). Per 256-triangle chunk: bbox test
// one-per-thread, ordered ballot/prefix compaction of survivor INDICES into
// LDS (order preserved -> reference tie-break). Survivor loop: index via
// ds_read_b32 + readfirstlane -> SGPR -> triangle coefficients come in as
// SCALAR loads from global (L2-resident), not LDS broadcast — the LDS pipe
// was the R5/R6 bottleneck (7 LDS instr/iter ~= 100% LDS-pipe duty).
// x2 parity accumulators x 2 px = 4 independent f64 chains/thread.
// ---------------------------------------------------------------------------
__global__ __launch_bounds__(256, 4) void k_raster(
    const double* __restrict__ tri,
    const float4* __restrict__ bbox,
    float* __restrict__ out_idx,
    int F) {
  __shared__ int s_idx[RCH];           // 1024 B
  __shared__ int s_wcnt[4];
  int n = blockIdx.z;
  int x = blockIdx.x * 16 + threadIdx.x;
  int yA = blockIdx.y * 32 + threadIdx.y;
  int yB = yA + 16;
  double px = (double)x;
  double pyA = (double)yA, pyB = (double)yB;
  // 0.5px guard band on bbox rejection.
  float tminx = (float)(blockIdx.x * 16) - 0.5f;
  float tmaxx = tminx + 16.0f;
  float tminy = (float)(blockIdx.y * 32) - 0.5f;
  float tmaxy = tminy + 32.0f;
  int tid = threadIdx.y * 16 + threadIdx.x;
  int wid = tid >> 6, lane = tid & 63;
  // parity-split accumulators (E=even u, O=odd u) per pixel A/B.
  // init EPS folds the reference's zi>EPS check into the strict-> update.
  double bEA = EPSD, bOA = EPSD, bEB = EPSD, bOB = EPSD;
  int iEA = -1, iOA = -1, iEB = -1, iOB = -1;
  const double* trin = tri + (size_t)n * F * 12;
  const float4* bbn = bbox + (size_t)n * F;

  auto proc = [&](int u, double& bstA, int& idA, double& bstB, int& idB) {
    int ti = __builtin_amdgcn_readfirstlane(s_idx[u]);
    const double* T = trin + (size_t)ti * 12;
    double EA0 = T[0], EB0 = T[1], EC0 = T[2];
    double EA1 = T[3], EB1 = T[4], EC1 = T[5];
    double EA2 = T[6], EB2 = T[7], EC2 = T[8];
    double R0 = T[9], R1 = T[10], R2 = T[11];
    double t0 = fma(px, EA0, EC0);
    double t1 = fma(px, EA1, EC1);
    double t2 = fma(px, EA2, EC2);
    // pixel A
    double W0 = fma(pyA, EB0, t0);
    double W1 = fma(pyA, EB1, t1);
    double W2 = fma(pyA, EB2, t2);
    double zi = fma(W0, R0, fma(W1, R1, W2 * R2));
    if ((W0 >= 0.0) & (W1 >= 0.0) & (W2 >= 0.0) & (zi > bstA)) { bstA = zi; idA = ti; }
    // pixel B
    W0 = fma(pyB, EB0, t0);
    W1 = fma(pyB, EB1, t1);
    W2 = fma(pyB, EB2, t2);
    zi = fma(W0, R0, fma(W1, R1, W2 * R2));
    if ((W0 >= 0.0) & (W1 >= 0.0) & (W2 >= 0.0) & (zi > bstB)) { bstB = zi; idB = ti; }
  };

  for (int c = 0; c < F; c += RCH) {
    int t = c + tid;
    bool surv = false;
    if (t < F) {
      float4 bb = bbn[t];
      surv = !(bb.z < tminx || bb.x > tmaxx || bb.w < tminy || bb.y > tmaxy);
    }
    unsigned long long m = __ballot(surv);
    int pre = __popcll(m & ((1ull << lane) - 1));
    __syncthreads();  // prior survivor-loop reads done before we overwrite
    if (lane == 0) s_wcnt[wid] = (int)__popcll(m);
    __syncthreads();
    int base = 0;
#pragma unroll
    for (int k = 0; k < 4; ++k)
      if (k < wid) base += s_wcnt[k];
    int total = s_wcnt[0] + s_wcnt[1] + s_wcnt[2] + s_wcnt[3];
    if (surv) s_idx[base + pre] = t;
    __syncthreads();
    int u = 0;
    for (; u + 1 < total; u += 2) {
      proc(u, bEA, iEA, bEB, iEB);
      proc(u + 1, bOA, iOA, bOB, iOB);
    }
    if (u < total) proc(u, bEA, iEA, bEB, iEB);
  }
  // merge parity accumulators: larger zi wins; exact tie -> smaller index
  // (unsigned cast makes -1 the weakest index).
  bool tOA = (bOA > bEA) || ((bOA == bEA) && ((unsigned)iOA < (unsigned)iEA));
  int outA = tOA ? iOA : iEA;
  bool tOB = (bOB > bEB) || ((bOB == bEB) && ((unsigned)iOB < (unsigned)iEB));
  int outB = tOB ? iOB : iEB;
  out_idx[((size_t)n * IMG_H + yA) * IMG_W + x] = (float)outA;
  out_idx[((size_t)n * IMG_H + yB) * IMG_W + x] = (float)outB;
}

// ---------------------------------------------------------------------------
// Kernel 4: interpolation + bilinear texture sample + remaining outputs (fp32;
// flat 40.96 thresholds make fp32-vs-f64 noise irrelevant here).
// ---------------------------------------------------------------------------
__global__ __launch_bounds__(256) void k_interp(
    const double* __restrict__ vpixd,
    const float* __restrict__ vt,
    const int* __restrict__ vi,
    const int* __restrict__ vti,
    const float* __restrict__ tex,
    float* __restrict__ out,
    int N, int V) {
#pragma clang fp contract(off)
  const int HW = IMG_H * IMG_W;
  int gid = blockIdx.x * blockDim.x + threadIdx.x;
  if (gid >= N * HW) return;
  int n = gid / HW;
  int p = gid - n * HW;
  int y = p / IMG_W;
  int x = p - y * IMG_W;
  size_t NHW = (size_t)N * HW;
  float* out_render = out;             // (N,3,H,W)
  float* out_mask = out + 3 * NHW;     // (N,H,W)
  float* out_depth = out + 4 * NHW;    // (N,H,W)
  float* out_vt = out + 5 * NHW;       // (N,H,W,2)
  float* out_bary = out + 7 * NHW;     // (N,3,H,W)
  float* out_idx = out + 10 * NHW;     // (N,H,W) written by k_raster

  int idx = (int)out_idx[gid];
  if (idx < 0) {
    for (int c = 0; c < 3; ++c) out_render[(size_t)(n * 3 + c) * HW + p] = 0.0f;
    out_mask[gid] = 0.0f;
    out_depth[gid] = 0.0f;
    out_vt[(size_t)gid * 2 + 0] = 0.0f;
    out_vt[(size_t)gid * 2 + 1] = 0.0f;
    for (int k = 0; k < 3; ++k) out_bary[(size_t)(n * 3 + k) * HW + p] = 0.0f;
    return;
  }
  int f0 = vi[idx * 3 + 0], f1 = vi[idx * 3 + 1], f2 = vi[idx * 3 + 2];
  int t0i = vti[idx * 3 + 0], t1i = vti[idx * 3 + 1], t2i = vti[idx * 3 + 2];
  const double* pv0 = vpixd + ((size_t)n * V + f0) * 3;
  const double* pv1 = vpixd + ((size_t)n * V + f1) * 3;
  const double* pv2 = vpixd + ((size_t)n * V + f2) * 3;
  float x0 = (float)pv0[0], y0 = (float)pv0[1], z0 = (float)pv0[2];
  float x1 = (float)pv1[0], y1 = (float)pv1[1], z1 = (float)pv1[2];
  float x2 = (float)pv2[0], y2 = (float)pv2[1], z2 = (float)pv2[2];
  float px = (float)x, py = (float)y;
  float w0 = (px - x1) * (y2 - y1) - (py - y1) * (x2 - x1);
  float w1 = (px - x2) * (y0 - y2) - (py - y2) * (x0 - x2);
  float w2 = (px - x0) * (y1 - y0) - (py - y0) * (x1 - x0);
  float area = (x2 - x0) * (y1 - y0) - (y2 - y0) * (x1 - x0);
  float sa = (fabsf(area) > EPSF) ? area : 1.0f;
  float b0 = w0 / sa, b1 = w1 / sa, b2 = w2 / sa;
  float zz0 = fmaxf(z0, EPSF), zz1 = fmaxf(z1, EPSF), zz2 = fmaxf(z2, EPSF);
  float bz0 = b0 / zz0, bz1 = b1 / zz1, bz2 = b2 / zz2;
  float zi = fmaxf((bz0 + bz1) + bz2, EPSF);
  float r0 = bz0 / zi, r1 = bz1 / zi, r2 = bz2 / zi;
  float depth = 1.0f / zi;
  float u0 = vt[(size_t)t0i * 2 + 0], q0 = 1.0f - vt[(size_t)t0i * 2 + 1];
  float u1 = vt[(size_t)t1i * 2 + 0], q1 = 1.0f - vt[(size_t)t1i * 2 + 1];
  float u2 = vt[(size_t)t2i * 2 + 0], q2 = 1.0f - vt[(size_t)t2i * 2 + 1];
  float vtx = (r0 * u0 + r1 * u1) + r2 * u2;
  float vty = (r0 * q0 + r1 * q1) + r2 * q2;
  float gx = vtx * 2.0f - 1.0f;
  float gy = vty * 2.0f - 1.0f;
  float ix = ((gx + 1.0f) * 0.5f) * (float)TEX_W - 0.5f;
  float iy = ((gy + 1.0f) * 0.5f) * (float)TEX_H - 0.5f;
  float x0f = floorf(ix), y0f = floorf(iy);
  float fx = ix - x0f, fy = iy - y0f;
  int x0i = min(max((int)x0f, 0), TEX_W - 1);
  int x1i = min(max((int)x0f + 1, 0), TEX_W - 1);
  int y0i = min(max((int)y0f, 0), TEX_H - 1);
  int y1i = min(max((int)y0f + 1, 0), TEX_H - 1);
  float omfx = 1.0f - fx, omfy = 1.0f - fy;
  for (int c = 0; c < 3; ++c) {
    const float* tc = tex + (size_t)(n * 3 + c) * TEX_H * TEX_W;
    float v00 = tc[(size_t)y0i * TEX_W + x0i];
    float v01 = tc[(size_t)y0i * TEX_W + x1i];
    float v10 = tc[(size_t)y1i * TEX_W + x0i];
    float v11 = tc[(size_t)y1i * TEX_W + x1i];
    float o = (v00 * omfx + v01 * fx) * omfy + (v10 * omfx + v11 * fx) * fy;
    out_render[(size_t)(n * 3 + c) * HW + p] = o;
  }
  out_mask[gid] = 1.0f;
  out_depth[gid] = depth;
  out_vt[(size_t)gid * 2 + 0] = vtx;
  out_vt[(size_t)gid * 2 + 1] = vty;
  out_bary[(size_t)(n * 3 + 0) * HW + p] = r0;
  out_bary[(size_t)(n * 3 + 1) * HW + p] = r1;
  out_bary[(size_t)(n * 3 + 2) * HW + p] = r2;
}

// ---------------------------------------------------------------------------
extern "C" void kernel_launch(void* const* d_in, const int* in_sizes, int n_in,
                              void* d_out, int out_size, void* d_ws, size_t ws_size,
                              hipStream_t stream) {
  const float* v = (const float*)d_in[0];
  const float* tex = (const float*)d_in[1];
  const float* vt = (const float*)d_in[2];
  const int* vi = (const int*)d_in[3];
  const int* vti = (const int*)d_in[4];
  const float* campos = (const float*)d_in[5];
  const float* camrot = (const float*)d_in[6];
  const float* focal = (const float*)d_in[7];
  const float* princpt = (const float*)d_in[8];
  int N = in_sizes[5] / 3;            // campos (N,3)
  int V = in_sizes[0] / (3 * N);      // v (N,V,3)
  int F = in_sizes[3] / 3;            // vi (F,3)

  char* wp = (char*)d_ws;
  double* vpixd = (double*)wp;
  wp += sizeof(double) * (size_t)N * V * 3;      // 196608 B
  double* tri = (double*)wp;
  wp += sizeof(double) * (size_t)N * F * 12;     // 393216 B
  float4* bbox = (float4*)wp;                    //  65536 B

  const int HW = IMG_H * IMG_W;
  float* out_idx = (float*)d_out + (size_t)10 * N * HW;

  int nv = N * V;
  k_project<<<(nv + 255) / 256, 256, 0, stream>>>(v, campos, camrot, focal,
                                                  princpt, vpixd, N, V);
  int nf = N * F;
  k_setup<<<(nf + 255) / 256, 256, 0, stream>>>(vpixd, vi, tri, bbox, N, V, F);
  dim3 rgrid(IMG_W / 16, IMG_H / 32, N);
  dim3 rblock(16, 16, 1);
  k_raster<<<rgrid, rblock, 0, stream>>>(tri, bbox, out_idx, F);
  int np = N * HW;
  k_interp<<<(np + 255) / 256, 256, 0, stream>>>(vpixd, vt, vi, vti, tex,
                                                 (float*)d_out, N, V);
}

// Round 8
// 300.663 us; speedup vs baseline: 1.4173x; 1.4173x over previous
//
#include <hip/hip_runtime.h>
#include <math.h>

#define EPSD 1e-8
#define EPSF 1e-8f
#define IMG_H 512
#define IMG_W 512
#define TEX_W 1024
#define TEX_H 1024
#define RCH 128    // triangles per compaction chunk (12.9 KB LDS)
#define SPLIT 2    // triangle-dimension split per tile

// ---------------------------------------------------------------------------
// Kernel 1: project vertices in f64 -> vpixd (x_pix, y_pix, z_cam)
// ---------------------------------------------------------------------------
__global__ __launch_bounds__(256) void k_project(
    const float* __restrict__ v,
    const float* __restrict__ campos,
    const float* __restrict__ camrot,
    const float* __restrict__ focal,
    const float* __restrict__ princpt,
    double* __restrict__ vpixd,
    int N, int V) {
#pragma clang fp contract(off)
  int i = blockIdx.x * blockDim.x + threadIdx.x;
  if (i >= N * V) return;
  int n = i / V;
  const float* vv = v + (size_t)i * 3;
  double ax = (double)vv[0] - (double)campos[n * 3 + 0];
  double ay = (double)vv[1] - (double)campos[n * 3 + 1];
  double az = (double)vv[2] - (double)campos[n * 3 + 2];
  const float* R = camrot + (size_t)n * 9;
  double cx = ((double)R[0] * ax + (double)R[1] * ay) + (double)R[2] * az;
  double cy = ((double)R[3] * ax + (double)R[4] * ay) + (double)R[5] * az;
  double cz = ((double)R[6] * ax + (double)R[7] * ay) + (double)R[8] * az;
  double zz = fmax(cz, EPSD);
  double xd = cx / zz;
  double yd = cy / zz;
  const float* Fc = focal + (size_t)n * 4;
  double px = ((double)Fc[0] * xd + (double)Fc[1] * yd) + (double)princpt[n * 2 + 0];
  double py = ((double)Fc[2] * xd + (double)Fc[3] * yd) + (double)princpt[n * 2 + 1];
  vpixd[(size_t)i * 3 + 0] = px;
  vpixd[(size_t)i * 3 + 1] = py;
  vpixd[(size_t)i * 3 + 2] = cz;
}

// ---------------------------------------------------------------------------
// Kernel 2: per-triangle coefficient setup (f64).   W_k = px*EA_k+py*EBn_k+EC_k
//   inside <=> all W_k>=0 ;  zi = W0*R0+W1*R1+W2*R2, R_k=1/(area^2*max(z,EPS))
// Invalid triangles: EA=EBn=0, EC=-1 -> never inside.
// Layout per (n,f): 6 x double2:
//  [0]=(EA0,EBn0) [1]=(EC0,EA1) [2]=(EBn1,EC1) [3]=(EA2,EBn2) [4]=(EC2,R0) [5]=(R1,R2)
// ---------------------------------------------------------------------------
__global__ __launch_bounds__(256) void k_setup(
    const double* __restrict__ vpixd,
    const int* __restrict__ vi,
    double2* __restrict__ tri,
    float4* __restrict__ bbox,
    int N, int V, int F) {
#pragma clang fp contract(off)
  int i = blockIdx.x * blockDim.x + threadIdx.x;
  if (i >= N * F) return;
  int n = i / F;
  int f = i - n * F;
  int i0 = vi[f * 3 + 0], i1 = vi[f * 3 + 1], i2 = vi[f * 3 + 2];
  const double* p0 = vpixd + ((size_t)n * V + i0) * 3;
  const double* p1 = vpixd + ((size_t)n * V + i1) * 3;
  const double* p2 = vpixd + ((size_t)n * V + i2) * 3;
  double x0 = p0[0], y0 = p0[1], z0 = p0[2];
  double x1 = p1[0], y1 = p1[1], z1 = p1[2];
  double x2 = p2[0], y2 = p2[1], z2 = p2[2];
  double A0 = y2 - y1, B0 = x2 - x1;
  double A1 = y0 - y2, B1 = x0 - x2;
  double A2 = y1 - y0, B2 = x1 - x0;
  double area = (x2 - x0) * A2 - (y2 - y0) * B2;
  bool valid = (fabs(area) > EPSD) && (z0 > EPSD) && (z1 > EPSD) && (z2 > EPSD);
  double s = area;
  double EA0 = 0.0, EBn0 = 0.0, EC0 = -1.0;
  double EA1 = 0.0, EBn1 = 0.0, EC1 = -1.0;
  double EA2 = 0.0, EBn2 = 0.0, EC2 = -1.0;
  double R0 = 0.0, R1 = 0.0, R2 = 0.0;
  if (valid) {
    EA0 = A0 * s; EBn0 = -(B0 * s); EC0 = (y1 * B0 - x1 * A0) * s;
    EA1 = A1 * s; EBn1 = -(B1 * s); EC1 = (y2 * B1 - x2 * A1) * s;
    EA2 = A2 * s; EBn2 = -(B2 * s); EC2 = (y0 * B2 - x0 * A2) * s;
    double s2 = s * s;
    R0 = 1.0 / (s2 * fmax(z0, EPSD));
    R1 = 1.0 / (s2 * fmax(z1, EPSD));
    R2 = 1.0 / (s2 * fmax(z2, EPSD));
  }
  double2* T = tri + (size_t)i * 6;
  T[0] = make_double2(EA0, EBn0);
  T[1] = make_double2(EC0, EA1);
  T[2] = make_double2(EBn1, EC1);
  T[3] = make_double2(EA2, EBn2);
  T[4] = make_double2(EC2, R0);
  T[5] = make_double2(R1, R2);
  float mnx = (float)fmin(x0, fmin(x1, x2));
  float mny = (float)fmin(y0, fmin(y1, y2));
  float mxx = (float)fmax(x0, fmax(x1, x2));
  float mxy = (float)fmax(y0, fmax(y1, y2));
  bbox[i] = make_float4(mnx, mny, mxx, mxy);
}

// ---------------------------------------------------------------------------
// Kernel 3: tiled rasterizer with triangle-split. 256-thread block covers a
// 16x32-pixel tile (2 px/thread) and scans HALF of F (blockIdx.z encodes
// image n and split s). This doubles blocks/CU to 8 -> 32 waves/CU with
// unchanged total work (passes/wave halve): pure latency-hiding gain over R5.
// Per 128-triangle chunk: ordered ballot/prefix compaction into LDS, then
// branchless survivor loop (x2 parity accumulators x 2 px = 4 indep chains).
// Writes per-split (zi_f64, idx) partials; exact merge in k_resolve.
// ---------------------------------------------------------------------------
__global__ __launch_bounds__(256, 8) void k_raster(
    const double2* __restrict__ tri,
    const float4* __restrict__ bbox,
    double* __restrict__ zpart,
    int* __restrict__ ipart,
    int F) {
  __shared__ double2 s_tri[RCH * 6];   // 12288 B
  __shared__ int s_idx[RCH];           //   512 B
  __shared__ int s_wcnt[4];
  int nz = blockIdx.z;
  int n = nz / SPLIT;
  int s = nz - n * SPLIT;
  int x = blockIdx.x * 16 + threadIdx.x;
  int yA = blockIdx.y * 32 + threadIdx.y;
  int yB = yA + 16;
  double px = (double)x;
  double pyA = (double)yA, pyB = (double)yB;
  float tminx = (float)(blockIdx.x * 16) - 0.5f;   // 0.5px guard band
  float tmaxx = tminx + 16.0f;
  float tminy = (float)(blockIdx.y * 32) - 0.5f;
  float tmaxy = tminy + 32.0f;
  int tid = threadIdx.y * 16 + threadIdx.x;
  int wid = tid >> 6, lane = tid & 63;
  // parity-split accumulators (E=even u, O=odd u) per pixel A/B.
  double bEA = EPSD, bOA = EPSD, bEB = EPSD, bOB = EPSD;
  int iEA = -1, iOA = -1, iEB = -1, iOB = -1;
  const double2* trin = tri + (size_t)n * F * 6;
  const float4* bbn = bbox + (size_t)n * F;
  int half = (F + SPLIT - 1) / SPLIT;
  int tbeg = s * half;
  int tend = min(F, tbeg + half);

  auto proc = [&](int u, double& bstA, int& idA, double& bstB, int& idB) {
    const double2* T = &s_tri[u * 6];
    double2 q0 = T[0], q1 = T[1], q2 = T[2], q3 = T[3], q4 = T[4], q5 = T[5];
    int ti = s_idx[u];
    double t0 = fma(px, q0.x, q1.x);   // px*EA0 + EC0
    double t1 = fma(px, q1.y, q2.y);   // px*EA1 + EC1
    double t2 = fma(px, q3.x, q4.x);   // px*EA2 + EC2
    double W0 = fma(pyA, q0.y, t0);
    double W1 = fma(pyA, q2.x, t1);
    double W2 = fma(pyA, q3.y, t2);
    double zi = fma(W0, q4.y, fma(W1, q5.x, W2 * q5.y));
    if ((W0 >= 0.0) & (W1 >= 0.0) & (W2 >= 0.0) & (zi > bstA)) { bstA = zi; idA = ti; }
    W0 = fma(pyB, q0.y, t0);
    W1 = fma(pyB, q2.x, t1);
    W2 = fma(pyB, q3.y, t2);
    zi = fma(W0, q4.y, fma(W1, q5.x, W2 * q5.y));
    if ((W0 >= 0.0) & (W1 >= 0.0) & (W2 >= 0.0) & (zi > bstB)) { bstB = zi; idB = ti; }
  };

  for (int c = tbeg; c < tend; c += RCH) {
    int t = c + tid;
    bool surv = false;
    if (tid < RCH && t < tend) {
      float4 bb = bbn[t];
      surv = !(bb.z < tminx || bb.x > tmaxx || bb.w < tminy || bb.y > tmaxy);
    }
    unsigned long long m = __ballot(surv);
    int pre = __popcll(m & ((1ull << lane) - 1));
    __syncthreads();  // prior survivor-loop reads done before we overwrite
    if (lane == 0) s_wcnt[wid] = (int)__popcll(m);
    __syncthreads();
    int base = 0;
#pragma unroll
    for (int k = 0; k < 4; ++k)
      if (k < wid) base += s_wcnt[k];
    int total = s_wcnt[0] + s_wcnt[1] + s_wcnt[2] + s_wcnt[3];
    if (surv) {
      int dst = base + pre;
      const double2* src = trin + (size_t)t * 6;
      double2* d = &s_tri[dst * 6];
      d[0] = src[0]; d[1] = src[1]; d[2] = src[2];
      d[3] = src[3]; d[4] = src[4]; d[5] = src[5];
      s_idx[dst] = t;
    }
    __syncthreads();
    int u = 0;
    for (; u + 1 < total; u += 2) {
      proc(u, bEA, iEA, bEB, iEB);
      proc(u + 1, bOA, iOA, bOB, iOB);
    }
    if (u < total) proc(u, bEA, iEA, bEB, iEB);
  }
  // merge parity accumulators: larger zi wins; exact tie -> smaller index.
  bool tOA = (bOA > bEA) || ((bOA == bEA) && ((unsigned)iOA < (unsigned)iEA));
  double zA = tOA ? bOA : bEA;
  int outA = tOA ? iOA : iEA;
  bool tOB = (bOB > bEB) || ((bOB == bEB) && ((unsigned)iOB < (unsigned)iEB));
  double zB = tOB ? bOB : bEB;
  int outB = tOB ? iOB : iEB;
  size_t NHW = (size_t)gridDim.z / SPLIT * IMG_H * IMG_W;
  size_t gA = (size_t)n * IMG_H * IMG_W + (size_t)yA * IMG_W + x;
  size_t gB = (size_t)n * IMG_H * IMG_W + (size_t)yB * IMG_W + x;
  zpart[(size_t)s * NHW + gA] = zA;
  ipart[(size_t)s * NHW + gA] = outA;
  zpart[(size_t)s * NHW + gB] = zB;
  ipart[(size_t)s * NHW + gB] = outB;
}

// ---------------------------------------------------------------------------
// Kernel 3b: exact merge of the SPLIT partials -> out_idx.
// Winner: max zi; exact tie -> smaller global index (== reference's ordered
// first-at-min scan). unsigned cast makes -1 the weakest index.
// ---------------------------------------------------------------------------
__global__ __launch_bounds__(256) void k_resolve(
    const double* __restrict__ zpart,
    const int* __restrict__ ipart,
    float* __restrict__ out_idx,
    int NHW) {
  int gid = blockIdx.x * blockDim.x + threadIdx.x;
  if (gid >= NHW) return;
  double z0 = zpart[gid], z1 = zpart[(size_t)NHW + gid];
  int i0 = ipart[gid], i1 = ipart[(size_t)NHW + gid];
  bool take1 = (z1 > z0) || ((z1 == z0) && ((unsigned)i1 < (unsigned)i0));
  out_idx[gid] = (float)(take1 ? i1 : i0);
}

// ---------------------------------------------------------------------------
// Kernel 4: interpolation + bilinear texture sample + remaining outputs.
// (Runs after k_resolve; overwrites the d_out slices used as partial scratch.)
// ---------------------------------------------------------------------------
__global__ __launch_bounds__(256) void k_interp(
    const double* __restrict__ vpixd,
    const float* __restrict__ vt,
    const int* __restrict__ vi,
    const int* __restrict__ vti,
    const float* __restrict__ tex,
    float* __restrict__ out,
    int N, int V) {
#pragma clang fp contract(off)
  const int HW = IMG_H * IMG_W;
  int gid = blockIdx.x * blockDim.x + threadIdx.x;
  if (gid >= N * HW) return;
  int n = gid / HW;
  int p = gid - n * HW;
  int y = p / IMG_W;
  int x = p - y * IMG_W;
  size_t NHW = (size_t)N * HW;
  float* out_render = out;             // (N,3,H,W)
  float* out_mask = out + 3 * NHW;     // (N,H,W)
  float* out_depth = out + 4 * NHW;    // (N,H,W)
  float* out_vt = out + 5 * NHW;       // (N,H,W,2)
  float* out_bary = out + 7 * NHW;     // (N,3,H,W)
  float* out_idx = out + 10 * NHW;     // (N,H,W) written by k_resolve

  int idx = (int)out_idx[gid];
  if (idx < 0) {
    for (int c = 0; c < 3; ++c) out_render[(size_t)(n * 3 + c) * HW + p] = 0.0f;
    out_mask[gid] = 0.0f;
    out_depth[gid] = 0.0f;
    out_vt[(size_t)gid * 2 + 0] = 0.0f;
    out_vt[(size_t)gid * 2 + 1] = 0.0f;
    for (int k = 0; k < 3; ++k) out_bary[(size_t)(n * 3 + k) * HW + p] = 0.0f;
    return;
  }
  int f0 = vi[idx * 3 + 0], f1 = vi[idx * 3 + 1], f2 = vi[idx * 3 + 2];
  int t0i = vti[idx * 3 + 0], t1i = vti[idx * 3 + 1], t2i = vti[idx * 3 + 2];
  const double* pv0 = vpixd + ((size_t)n * V + f0) * 3;
  const double* pv1 = vpixd + ((size_t)n * V + f1) * 3;
  const double* pv2 = vpixd + ((size_t)n * V + f2) * 3;
  float x0 = (float)pv0[0], y0 = (float)pv0[1], z0 = (float)pv0[2];
  float x1 = (float)pv1[0], y1 = (float)pv1[1], z1 = (float)pv1[2];
  float x2 = (float)pv2[0], y2 = (float)pv2[1], z2 = (float)pv2[2];
  float px = (float)x, py = (float)y;
  float w0 = (px - x1) * (y2 - y1) - (py - y1) * (x2 - x1);
  float w1 = (px - x2) * (y0 - y2) - (py - y2) * (x0 - x2);
  float w2 = (px - x0) * (y1 - y0) - (py - y0) * (x1 - x0);
  float area = (x2 - x0) * (y1 - y0) - (y2 - y0) * (x1 - x0);
  float sa = (fabsf(area) > EPSF) ? area : 1.0f;
  float b0 = w0 / sa, b1 = w1 / sa, b2 = w2 / sa;
  float zz0 = fmaxf(z0, EPSF), zz1 = fmaxf(z1, EPSF), zz2 = fmaxf(z2, EPSF);
  float bz0 = b0 / zz0, bz1 = b1 / zz1, bz2 = b2 / zz2;
  float zi = fmaxf((bz0 + bz1) + bz2, EPSF);
  float r0 = bz0 / zi, r1 = bz1 / zi, r2 = bz2 / zi;
  float depth = 1.0f / zi;
  float u0 = vt[(size_t)t0i * 2 + 0], q0 = 1.0f - vt[(size_t)t0i * 2 + 1];
  float u1 = vt[(size_t)t1i * 2 + 0], q1 = 1.0f - vt[(size_t)t1i * 2 + 1];
  float u2 = vt[(size_t)t2i * 2 + 0], q2 = 1.0f - vt[(size_t)t2i * 2 + 1];
  float vtx = (r0 * u0 + r1 * u1) + r2 * u2;
  float vty = (r0 * q0 + r1 * q1) + r2 * q2;
  float gx = vtx * 2.0f - 1.0f;
  float gy = vty * 2.0f - 1.0f;
  float ix = ((gx + 1.0f) * 0.5f) * (float)TEX_W - 0.5f;
  float iy = ((gy + 1.0f) * 0.5f) * (float)TEX_H - 0.5f;
  float x0f = floorf(ix), y0f = floorf(iy);
  float fx = ix - x0f, fy = iy - y0f;
  int x0i = min(max((int)x0f, 0), TEX_W - 1);
  int x1i = min(max((int)x0f + 1, 0), TEX_W - 1);
  int y0i = min(max((int)y0f, 0), TEX_H - 1);
  int y1i = min(max((int)y0f + 1, 0), TEX_H - 1);
  float omfx = 1.0f - fx, omfy = 1.0f - fy;
  for (int c = 0; c < 3; ++c) {
    const float* tc = tex + (size_t)(n * 3 + c) * TEX_H * TEX_W;
    float v00 = tc[(size_t)y0i * TEX_W + x0i];
    float v01 = tc[(size_t)y0i * TEX_W + x1i];
    float v10 = tc[(size_t)y1i * TEX_W + x0i];
    float v11 = tc[(size_t)y1i * TEX_W + x1i];
    float o = (v00 * omfx + v01 * fx) * omfy + (v10 * omfx + v11 * fx) * fy;
    out_render[(size_t)(n * 3 + c) * HW + p] = o;
  }
  out_mask[gid] = 1.0f;
  out_depth[gid] = depth;
  out_vt[(size_t)gid * 2 + 0] = vtx;
  out_vt[(size_t)gid * 2 + 1] = vty;
  out_bary[(size_t)(n * 3 + 0) * HW + p] = r0;
  out_bary[(size_t)(n * 3 + 1) * HW + p] = r1;
  out_bary[(size_t)(n * 3 + 2) * HW + p] = r2;
}

// ---------------------------------------------------------------------------
extern "C" void kernel_launch(void* const* d_in, const int* in_sizes, int n_in,
                              void* d_out, int out_size, void* d_ws, size_t ws_size,
                              hipStream_t stream) {
  const float* v = (const float*)d_in[0];
  const float* tex = (const float*)d_in[1];
  const float* vt = (const float*)d_in[2];
  const int* vi = (const int*)d_in[3];
  const int* vti = (const int*)d_in[4];
  const float* campos = (const float*)d_in[5];
  const float* camrot = (const float*)d_in[6];
  const float* focal = (const float*)d_in[7];
  const float* princpt = (const float*)d_in[8];
  int N = in_sizes[5] / 3;            // campos (N,3)
  int V = in_sizes[0] / (3 * N);      // v (N,V,3)
  int F = in_sizes[3] / 3;            // vi (F,3)

  char* wp = (char*)d_ws;
  double* vpixd = (double*)wp;
  wp += sizeof(double) * (size_t)N * V * 3;      // 196608 B
  double2* tri = (double2*)wp;
  wp += sizeof(double2) * (size_t)N * F * 6;     // 393216 B
  float4* bbox = (float4*)wp;                    //  65536 B

  const int HW = IMG_H * IMG_W;
  const size_t NHW = (size_t)N * HW;
  // Partial (zi, idx) scratch carved from d_out slices 0..6 (render/mask/
  // depth/vt = 7*NHW floats = 14.7 MB >= SPLIT*NHW*12 B = 12.6 MB). These
  // slices are rewritten by k_interp AFTER k_resolve has consumed the
  // partials — strict launch ordering on one stream, no race.
  double* zpart = (double*)d_out;                          // SPLIT*NHW*8 B
  int* ipart = (int*)((char*)d_out + SPLIT * NHW * 8);     // SPLIT*NHW*4 B
  float* out_idx = (float*)d_out + (size_t)10 * NHW;

  int nv = N * V;
  k_project<<<(nv + 255) / 256, 256, 0, stream>>>(v, campos, camrot, focal,
                                                  princpt, vpixd, N, V);
  int nf = N * F;
  k_setup<<<(nf + 255) / 256, 256, 0, stream>>>(vpixd, vi, tri, bbox, N, V, F);
  dim3 rgrid(IMG_W / 16, IMG_H / 32, N * SPLIT);
  dim3 rblock(16, 16, 1);
  k_raster<<<rgrid, rblock, 0, stream>>>(tri, bbox, zpart, ipart, F);
  k_resolve<<<((int)NHW + 255) / 256, 256, 0, stream>>>(zpart, ipart, out_idx,
                                                        (int)NHW);
  int np = N * HW;
  k_interp<<<(np + 255) / 256, 256, 0, stream>>>(vpixd, vt, vi, vti, tex,
                                                 (float*)d_out, N, V);
}

// Round 9
// 286.056 us; speedup vs baseline: 1.4896x; 1.0511x over previous
//
#include <hip/hip_runtime.h>
#include <math.h>

#define EPSD 1e-8
#define EPSF 1e-8f
#define IMG_H 512
#define IMG_W 512
#define TEX_W 1024
#define TEX_H 1024
#define RCH 128    // triangles per compaction chunk (12.9 KB LDS)
#define SPLIT 2    // triangle-dimension split per tile

// ---------------------------------------------------------------------------
// Kernel 1: project vertices in f64 -> vpixd (x_pix, y_pix, z_cam)
// ---------------------------------------------------------------------------
__global__ __launch_bounds__(256) void k_project(
    const float* __restrict__ v,
    const float* __restrict__ campos,
    const float* __restrict__ camrot,
    const float* __restrict__ focal,
    const float* __restrict__ princpt,
    double* __restrict__ vpixd,
    int N, int V) {
#pragma clang fp contract(off)
  int i = blockIdx.x * blockDim.x + threadIdx.x;
  if (i >= N * V) return;
  int n = i / V;
  const float* vv = v + (size_t)i * 3;
  double ax = (double)vv[0] - (double)campos[n * 3 + 0];
  double ay = (double)vv[1] - (double)campos[n * 3 + 1];
  double az = (double)vv[2] - (double)campos[n * 3 + 2];
  const float* R = camrot + (size_t)n * 9;
  double cx = ((double)R[0] * ax + (double)R[1] * ay) + (double)R[2] * az;
  double cy = ((double)R[3] * ax + (double)R[4] * ay) + (double)R[5] * az;
  double cz = ((double)R[6] * ax + (double)R[7] * ay) + (double)R[8] * az;
  double zz = fmax(cz, EPSD);
  double xd = cx / zz;
  double yd = cy / zz;
  const float* Fc = focal + (size_t)n * 4;
  double px = ((double)Fc[0] * xd + (double)Fc[1] * yd) + (double)princpt[n * 2 + 0];
  double py = ((double)Fc[2] * xd + (double)Fc[3] * yd) + (double)princpt[n * 2 + 1];
  vpixd[(size_t)i * 3 + 0] = px;
  vpixd[(size_t)i * 3 + 1] = py;
  vpixd[(size_t)i * 3 + 2] = cz;
}

// ---------------------------------------------------------------------------
// Kernel 2: per-triangle coefficient setup (f64).
//   W_k = px*EA_k + py*EB_k + EC_k ; inside <=> all W_k >= 0
//   zi  = px*P + py*S + Q  where P=sum(EA_k*R_k), S=sum(EB_k*R_k),
//         Q=sum(EC_k*R_k), R_k = 1/(area^2*max(z_k,EPS))
// Invalid triangles: EA=EB=0, EC=-1, P=Q=S=0 -> never inside.
// Layout per (n,f), 6 x double2:
//  [0]=(EA0,EB0) [1]=(EC0,EA1) [2]=(EB1,EC1) [3]=(EA2,EB2) [4]=(EC2,P) [5]=(Q,S)
// ---------------------------------------------------------------------------
__global__ __launch_bounds__(256) void k_setup(
    const double* __restrict__ vpixd,
    const int* __restrict__ vi,
    double2* __restrict__ tri,
    float4* __restrict__ bbox,
    int N, int V, int F) {
#pragma clang fp contract(off)
  int i = blockIdx.x * blockDim.x + threadIdx.x;
  if (i >= N * F) return;
  int n = i / F;
  int f = i - n * F;
  int i0 = vi[f * 3 + 0], i1 = vi[f * 3 + 1], i2 = vi[f * 3 + 2];
  const double* p0 = vpixd + ((size_t)n * V + i0) * 3;
  const double* p1 = vpixd + ((size_t)n * V + i1) * 3;
  const double* p2 = vpixd + ((size_t)n * V + i2) * 3;
  double x0 = p0[0], y0 = p0[1], z0 = p0[2];
  double x1 = p1[0], y1 = p1[1], z1 = p1[2];
  double x2 = p2[0], y2 = p2[1], z2 = p2[2];
  double A0 = y2 - y1, B0 = x2 - x1;
  double A1 = y0 - y2, B1 = x0 - x2;
  double A2 = y1 - y0, B2 = x1 - x0;
  double area = (x2 - x0) * A2 - (y2 - y0) * B2;
  bool valid = (fabs(area) > EPSD) && (z0 > EPSD) && (z1 > EPSD) && (z2 > EPSD);
  double s = area;
  double EA0 = 0.0, EB0 = 0.0, EC0 = -1.0;
  double EA1 = 0.0, EB1 = 0.0, EC1 = -1.0;
  double EA2 = 0.0, EB2 = 0.0, EC2 = -1.0;
  double P = 0.0, Q = 0.0, S = 0.0;
  if (valid) {
    EA0 = A0 * s; EB0 = -(B0 * s); EC0 = (y1 * B0 - x1 * A0) * s;
    EA1 = A1 * s; EB1 = -(B1 * s); EC1 = (y2 * B1 - x2 * A1) * s;
    EA2 = A2 * s; EB2 = -(B2 * s); EC2 = (y0 * B2 - x0 * A2) * s;
    double s2 = s * s;
    double R0 = 1.0 / (s2 * fmax(z0, EPSD));
    double R1 = 1.0 / (s2 * fmax(z1, EPSD));
    double R2 = 1.0 / (s2 * fmax(z2, EPSD));
    P = EA0 * R0 + EA1 * R1 + EA2 * R2;
    S = EB0 * R0 + EB1 * R1 + EB2 * R2;
    Q = EC0 * R0 + EC1 * R1 + EC2 * R2;
  }
  double2* T = tri + (size_t)i * 6;
  T[0] = make_double2(EA0, EB0);
  T[1] = make_double2(EC0, EA1);
  T[2] = make_double2(EB1, EC1);
  T[3] = make_double2(EA2, EB2);
  T[4] = make_double2(EC2, P);
  T[5] = make_double2(Q, S);
  float mnx = (float)fmin(x0, fmin(x1, x2));
  float mny = (float)fmin(y0, fmin(y1, y2));
  float mxx = (float)fmax(x0, fmax(x1, x2));
  float mxy = (float)fmax(y0, fmax(y1, y2));
  bbox[i] = make_float4(mnx, mny, mxx, mxy);
}

// ---------------------------------------------------------------------------
// Kernel 3: tiled rasterizer with triangle-split. 256-thread block covers a
// 16x32-pixel tile (2 px/thread) and scans half of F. Per 128-triangle
// chunk: ordered ballot/prefix compaction into LDS, then a branchless
// survivor loop with explicit 1-ahead register prefetch (two half-stages:
// n0..n2+idx before part-1 compute, n3..n5 before part-2). inside-test via
// sign-bit OR folded into zi's high word (sign set -> NaN -> never wins).
// zi costs 1 FMA/px via precomputed P,Q,S. Exact merge in k_resolve.
// ---------------------------------------------------------------------------
__global__ __launch_bounds__(256, 8) void k_raster(
    const double2* __restrict__ tri,
    const float4* __restrict__ bbox,
    double* __restrict__ zpart,
    int* __restrict__ ipart,
    int F) {
  __shared__ double2 s_tri[RCH * 6];   // 12288 B
  __shared__ int s_idx[RCH];           //   512 B
  __shared__ int s_wcnt[4];
  int nz = blockIdx.z;
  int n = nz / SPLIT;
  int s = nz - n * SPLIT;
  int x = blockIdx.x * 16 + threadIdx.x;
  int yA = blockIdx.y * 32 + threadIdx.y;
  int yB = yA + 16;
  double px = (double)x;
  double pyA = (double)yA, pyB = (double)yB;
  float tminx = (float)(blockIdx.x * 16) - 0.5f;   // 0.5px guard band
  float tmaxx = tminx + 16.0f;
  float tminy = (float)(blockIdx.y * 32) - 0.5f;
  float tmaxy = tminy + 32.0f;
  int tid = threadIdx.y * 16 + threadIdx.x;
  int wid = tid >> 6, lane = tid & 63;
  // single accumulator per pixel; init EPS folds zi>EPS into strict->.
  double bA = EPSD, bB = EPSD;
  int iA = -1, iB = -1;
  const double2* trin = tri + (size_t)n * F * 6;
  const float4* bbn = bbox + (size_t)n * F;
  int half = (F + SPLIT - 1) / SPLIT;
  int tbeg = s * half;
  int tend = min(F, tbeg + half);

  for (int c = tbeg; c < tend; c += RCH) {
    int t = c + tid;
    bool surv = false;
    if (tid < RCH && t < tend) {
      float4 bb = bbn[t];
      surv = !(bb.z < tminx || bb.x > tmaxx || bb.w < tminy || bb.y > tmaxy);
    }
    unsigned long long m = __ballot(surv);
    int pre = __popcll(m & ((1ull << lane) - 1));
    __syncthreads();  // prior survivor-loop reads done before we overwrite
    if (lane == 0) s_wcnt[wid] = (int)__popcll(m);
    __syncthreads();
    int base = 0;
#pragma unroll
    for (int k = 0; k < 4; ++k)
      if (k < wid) base += s_wcnt[k];
    int total = s_wcnt[0] + s_wcnt[1] + s_wcnt[2] + s_wcnt[3];
    if (surv) {
      int dst = base + pre;
      const double2* src = trin + (size_t)t * 6;
      double2* d = &s_tri[dst * 6];
      d[0] = src[0]; d[1] = src[1]; d[2] = src[2];
      d[3] = src[3]; d[4] = src[4]; d[5] = src[5];
      s_idx[dst] = t;
    }
    __syncthreads();
    if (total > 0) {
      int last = total - 1;
      double2 c0, c1, c2, c3, c4, c5;
      {
        const double2* T = &s_tri[0];
        c0 = T[0]; c1 = T[1]; c2 = T[2]; c3 = T[3]; c4 = T[4]; c5 = T[5];
      }
      int ti = s_idx[0];
      for (int u = 0; u < total; ++u) {
        int un = min(u + 1, last);
        const double2* Tn = &s_tri[un * 6];
        // prefetch half 1 (+ index) for tri u+1
        double2 n0 = Tn[0], n1 = Tn[1], n2 = Tn[2];
        int tn = s_idx[un];
        // part 1: uses c0..c2
        double t0 = fma(px, c0.x, c1.x);    // px*EA0 + EC0
        double t1 = fma(px, c1.y, c2.y);    // px*EA1 + EC1
        double W0A = fma(pyA, c0.y, t0);
        double W1A = fma(pyA, c2.x, t1);
        double W0B = fma(pyB, c0.y, t0);
        double W1B = fma(pyB, c2.x, t1);
        // prefetch half 2 for tri u+1
        double2 n3 = Tn[3], n4 = Tn[4], n5 = Tn[5];
        // part 2: uses c3..c5
        double t2 = fma(px, c3.x, c4.x);    // px*EA2 + EC2
        double uu = fma(px, c4.y, c5.x);    // px*P + Q
        double W2A = fma(pyA, c3.y, t2);
        double ziA = fma(pyA, c5.y, uu);
        double W2B = fma(pyB, c3.y, t2);
        double ziB = fma(pyB, c5.y, uu);
        // inside-fold: any W sign bit -> poison zi to NaN (compares false)
        int mA = (__double2hiint(W0A) | __double2hiint(W1A) |
                  __double2hiint(W2A)) >> 31;
        ziA = __hiloint2double(__double2hiint(ziA) | mA, __double2loint(ziA));
        if (ziA > bA) { bA = ziA; iA = ti; }
        int mB = (__double2hiint(W0B) | __double2hiint(W1B) |
                  __double2hiint(W2B)) >> 31;
        ziB = __hiloint2double(__double2hiint(ziB) | mB, __double2loint(ziB));
        if (ziB > bB) { bB = ziB; iB = ti; }
        // rotate
        c0 = n0; c1 = n1; c2 = n2; c3 = n3; c4 = n4; c5 = n5; ti = tn;
      }
    }
  }
  size_t NHW = (size_t)gridDim.z / SPLIT * IMG_H * IMG_W;
  size_t gA = (size_t)n * IMG_H * IMG_W + (size_t)yA * IMG_W + x;
  size_t gB = (size_t)n * IMG_H * IMG_W + (size_t)yB * IMG_W + x;
  zpart[(size_t)s * NHW + gA] = bA;
  ipart[(size_t)s * NHW + gA] = iA;
  zpart[(size_t)s * NHW + gB] = bB;
  ipart[(size_t)s * NHW + gB] = iB;
}

// ---------------------------------------------------------------------------
// Kernel 3b: exact merge of the SPLIT partials -> out_idx.
// Winner: max zi; exact tie -> smaller global index (== reference's ordered
// first-at-min scan). unsigned cast makes -1 the weakest index.
// ---------------------------------------------------------------------------
__global__ __launch_bounds__(256) void k_resolve(
    const double* __restrict__ zpart,
    const int* __restrict__ ipart,
    float* __restrict__ out_idx,
    int NHW) {
  int gid = blockIdx.x * blockDim.x + threadIdx.x;
  if (gid >= NHW) return;
  double z0 = zpart[gid], z1 = zpart[(size_t)NHW + gid];
  int i0 = ipart[gid], i1 = ipart[(size_t)NHW + gid];
  bool take1 = (z1 > z0) || ((z1 == z0) && ((unsigned)i1 < (unsigned)i0));
  out_idx[gid] = (float)(take1 ? i1 : i0);
}

// ---------------------------------------------------------------------------
// Kernel 4: interpolation + bilinear texture sample + remaining outputs.
// (Runs after k_resolve; overwrites the d_out slices used as partial scratch.)
// ---------------------------------------------------------------------------
__global__ __launch_bounds__(256) void k_interp(
    const double* __restrict__ vpixd,
    const float* __restrict__ vt,
    const int* __restrict__ vi,
    const int* __restrict__ vti,
    const float* __restrict__ tex,
    float* __restrict__ out,
    int N, int V) {
#pragma clang fp contract(off)
  const int HW = IMG_H * IMG_W;
  int gid = blockIdx.x * blockDim.x + threadIdx.x;
  if (gid >= N * HW) return;
  int n = gid / HW;
  int p = gid - n * HW;
  int y = p / IMG_W;
  int x = p - y * IMG_W;
  size_t NHW = (size_t)N * HW;
  float* out_render = out;             // (N,3,H,W)
  float* out_mask = out + 3 * NHW;     // (N,H,W)
  float* out_depth = out + 4 * NHW;    // (N,H,W)
  float* out_vt = out + 5 * NHW;       // (N,H,W,2)
  float* out_bary = out + 7 * NHW;     // (N,3,H,W)
  float* out_idx = out + 10 * NHW;     // (N,H,W) written by k_resolve

  int idx = (int)out_idx[gid];
  if (idx < 0) {
    for (int c = 0; c < 3; ++c) out_render[(size_t)(n * 3 + c) * HW + p] = 0.0f;
    out_mask[gid] = 0.0f;
    out_depth[gid] = 0.0f;
    out_vt[(size_t)gid * 2 + 0] = 0.0f;
    out_vt[(size_t)gid * 2 + 1] = 0.0f;
    for (int k = 0; k < 3; ++k) out_bary[(size_t)(n * 3 + k) * HW + p] = 0.0f;
    return;
  }
  int f0 = vi[idx * 3 + 0], f1 = vi[idx * 3 + 1], f2 = vi[idx * 3 + 2];
  int t0i = vti[idx * 3 + 0], t1i = vti[idx * 3 + 1], t2i = vti[idx * 3 + 2];
  const double* pv0 = vpixd + ((size_t)n * V + f0) * 3;
  const double* pv1 = vpixd + ((size_t)n * V + f1) * 3;
  const double* pv2 = vpixd + ((size_t)n * V + f2) * 3;
  float x0 = (float)pv0[0], y0 = (float)pv0[1], z0 = (float)pv0[2];
  float x1 = (float)pv1[0], y1 = (float)pv1[1], z1 = (float)pv1[2];
  float x2 = (float)pv2[0], y2 = (float)pv2[1], z2 = (float)pv2[2];
  float px = (float)x, py = (float)y;
  float w0 = (px - x1) * (y2 - y1) - (py - y1) * (x2 - x1);
  float w1 = (px - x2) * (y0 - y2) - (py - y2) * (x0 - x2);
  float w2 = (px - x0) * (y1 - y0) - (py - y0) * (x1 - x0);
  float area = (x2 - x0) * (y1 - y0) - (y2 - y0) * (x1 - x0);
  float sa = (fabsf(area) > EPSF) ? area : 1.0f;
  float b0 = w0 / sa, b1 = w1 / sa, b2 = w2 / sa;
  float zz0 = fmaxf(z0, EPSF), zz1 = fmaxf(z1, EPSF), zz2 = fmaxf(z2, EPSF);
  float bz0 = b0 / zz0, bz1 = b1 / zz1, bz2 = b2 / zz2;
  float zi = fmaxf((bz0 + bz1) + bz2, EPSF);
  float r0 = bz0 / zi, r1 = bz1 / zi, r2 = bz2 / zi;
  float depth = 1.0f / zi;
  float u0 = vt[(size_t)t0i * 2 + 0], q0 = 1.0f - vt[(size_t)t0i * 2 + 1];
  float u1 = vt[(size_t)t1i * 2 + 0], q1 = 1.0f - vt[(size_t)t1i * 2 + 1];
  float u2 = vt[(size_t)t2i * 2 + 0], q2 = 1.0f - vt[(size_t)t2i * 2 + 1];
  float vtx = (r0 * u0 + r1 * u1) + r2 * u2;
  float vty = (r0 * q0 + r1 * q1) + r2 * q2;
  float gx = vtx * 2.0f - 1.0f;
  float gy = vty * 2.0f - 1.0f;
  float ix = ((gx + 1.0f) * 0.5f) * (float)TEX_W - 0.5f;
  float iy = ((gy + 1.0f) * 0.5f) * (float)TEX_H - 0.5f;
  float x0f = floorf(ix), y0f = floorf(iy);
  float fx = ix - x0f, fy = iy - y0f;
  int x0i = min(max((int)x0f, 0), TEX_W - 1);
  int x1i = min(max((int)x0f + 1, 0), TEX_W - 1);
  int y0i = min(max((int)y0f, 0), TEX_H - 1);
  int y1i = min(max((int)y0f + 1, 0), TEX_H - 1);
  float omfx = 1.0f - fx, omfy = 1.0f - fy;
  for (int c = 0; c < 3; ++c) {
    const float* tc = tex + (size_t)(n * 3 + c) * TEX_H * TEX_W;
    float v00 = tc[(size_t)y0i * TEX_W + x0i];
    float v01 = tc[(size_t)y0i * TEX_W + x1i];
    float v10 = tc[(size_t)y1i * TEX_W + x0i];
    float v11 = tc[(size_t)y1i * TEX_W + x1i];
    float o = (v00 * omfx + v01 * fx) * omfy + (v10 * omfx + v11 * fx) * fy;
    out_render[(size_t)(n * 3 + c) * HW + p] = o;
  }
  out_mask[gid] = 1.0f;
  out_depth[gid] = depth;
  out_vt[(size_t)gid * 2 + 0] = vtx;
  out_vt[(size_t)gid * 2 + 1] = vty;
  out_bary[(size_t)(n * 3 + 0) * HW + p] = r0;
  out_bary[(size_t)(n * 3 + 1) * HW + p] = r1;
  out_bary[(size_t)(n * 3 + 2) * HW + p] = r2;
}

// ---------------------------------------------------------------------------
extern "C" void kernel_launch(void* const* d_in, const int* in_sizes, int n_in,
                              void* d_out, int out_size, void* d_ws, size_t ws_size,
                              hipStream_t stream) {
  const float* v = (const float*)d_in[0];
  const float* tex = (const float*)d_in[1];
  const float* vt = (const float*)d_in[2];
  const int* vi = (const int*)d_in[3];
  const int* vti = (const int*)d_in[4];
  const float* campos = (const float*)d_in[5];
  const float* camrot = (const float*)d_in[6];
  const float* focal = (const float*)d_in[7];
  const float* princpt = (const float*)d_in[8];
  int N = in_sizes[5] / 3;            // campos (N,3)
  int V = in_sizes[0] / (3 * N);      // v (N,V,3)
  int F = in_sizes[3] / 3;            // vi (F,3)

  char* wp = (char*)d_ws;
  double* vpixd = (double*)wp;
  wp += sizeof(double) * (size_t)N * V * 3;      // 196608 B
  double2* tri = (double2*)wp;
  wp += sizeof(double2) * (size_t)N * F * 6;     // 393216 B
  float4* bbox = (float4*)wp;                    //  65536 B

  const int HW = IMG_H * IMG_W;
  const size_t NHW = (size_t)N * HW;
  // Partial (zi, idx) scratch carved from d_out slices 0..6 (14.7 MB >=
  // SPLIT*NHW*12 B = 12.6 MB). k_interp rewrites those slices only AFTER
  // k_resolve has consumed the partials — strict stream ordering, no race.
  double* zpart = (double*)d_out;                          // SPLIT*NHW*8 B
  int* ipart = (int*)((char*)d_out + SPLIT * NHW * 8);     // SPLIT*NHW*4 B
  float* out_idx = (float*)d_out + (size_t)10 * NHW;

  int nv = N * V;
  k_project<<<(nv + 255) / 256, 256, 0, stream>>>(v, campos, camrot, focal,
                                                  princpt, vpixd, N, V);
  int nf = N * F;
  k_setup<<<(nf + 255) / 256, 256, 0, stream>>>(vpixd, vi, tri, bbox, N, V, F);
  dim3 rgrid(IMG_W / 16, IMG_H / 32, N * SPLIT);
  dim3 rblock(16, 16, 1);
  k_raster<<<rgrid, rblock, 0, stream>>>(tri, bbox, zpart, ipart, F);
  k_resolve<<<((int)NHW + 255) / 256, 256, 0, stream>>>(zpart, ipart, out_idx,
                                                        (int)NHW);
  int np = N * HW;
  k_interp<<<(np + 255) / 256, 256, 0, stream>>>(vpixd, vt, vi, vti, tex,
                                                 (float*)d_out, N, V);
}